// Round 2
// baseline (1285.386 us; speedup 1.0000x reference)
//
#include <hip/hip_runtime.h>
#include <stdint.h>

#define V_ 32000
#define E_ 512
#define H_ 1024
#define B_ 16
#define S_ 128
#define K_ 15

typedef float floatx4 __attribute__((ext_vector_type(4)));
typedef short shortx8 __attribute__((ext_vector_type(8)));
typedef __bf16 bf16x8 __attribute__((ext_vector_type(8)));

static __device__ __forceinline__ unsigned short f2b(float f) {
  union { float f; uint32_t u; } v; v.f = f;
  uint32_t u = v.u;
  u += 0x7FFFu + ((u >> 16) & 1u);   // round-to-nearest-even
  return (unsigned short)(u >> 16);
}

static __device__ __forceinline__ shortx8 cvt8(floatx4 a, floatx4 b) {
  shortx8 r;
  r[0] = (short)f2b(a[0]); r[1] = (short)f2b(a[1]);
  r[2] = (short)f2b(a[2]); r[3] = (short)f2b(a[3]);
  r[4] = (short)f2b(b[0]); r[5] = (short)f2b(b[1]);
  r[6] = (short)f2b(b[2]); r[7] = (short)f2b(b[3]);
  return r;
}

static __device__ __forceinline__ floatx4 mfma_bf16(shortx8 a, shortx8 b, floatx4 c) {
  return __builtin_amdgcn_mfma_f32_16x16x32_bf16(
      __builtin_bit_cast(bf16x8, a), __builtin_bit_cast(bf16x8, b), c, 0, 0, 0);
}

// ---------------- tiny kernels ----------------

__global__ void k_zero(int* __restrict__ p, int n) {
  int i = blockIdx.x * blockDim.x + threadIdx.x;
  if (i < n) p[i] = 0;
}

// topic[n] = sum_k theta[k] * beta[k][n]   (grid 125x256 == 32000 exactly)
__global__ void k_topic(const float* __restrict__ beta, const float* __restrict__ theta,
                        float* __restrict__ topic) {
  int n = blockIdx.x * blockDim.x + threadIdx.x;
  float s = 0.f;
#pragma unroll
  for (int k = 0; k < K_; ++k) s += theta[k] * beta[k * V_ + n];
  topic[n] = s;
}

// fp32 -> bf16, 8 elems/thread. grid*block*8 must equal n exactly.
__global__ void k_cvt(const float* __restrict__ src, unsigned short* __restrict__ dst) {
  size_t i = (size_t)(blockIdx.x * blockDim.x + threadIdx.x) * 8;
  floatx4 f0 = *(const floatx4*)(src + i);
  floatx4 f1 = *(const floatx4*)(src + i + 4);
  *(shortx8*)(dst + i) = cvt8(f0, f1);
}

// ---------------- pre-projection GEMM ----------------
// pre[m=t*16+b][n] = sum_e W_emb[ids[b][t]][e]*W_ih[n][e] + b_ih[n] + b_hh[n]
// M=2048, N=1024, K=512. grid (N/128=8, M/128=16), 256 threads.
__global__ __launch_bounds__(256, 2) void k_gemm_pre(
    const int* __restrict__ ids, const float* __restrict__ W_emb,
    const float* __restrict__ W_ih, const float* __restrict__ b_ih,
    const float* __restrict__ b_hh, float* __restrict__ pre) {
  __shared__ unsigned short As[128 * 72];
  __shared__ unsigned short Bs[128 * 72];
  const int tid = threadIdx.x;
  const int gn0 = blockIdx.x * 128;
  const int gm0 = blockIdx.y * 128;
  const int wave = tid >> 6, lane = tid & 63;
  const int wm = (wave >> 1) * 64, wn = (wave & 1) * 64;
  const int lr = lane & 15, lg = lane >> 4;

  floatx4 acc[4][4];
#pragma unroll
  for (int i = 0; i < 4; ++i)
#pragma unroll
    for (int j = 0; j < 4; ++j) acc[i][j] = (floatx4)0.0f;

  for (int k0 = 0; k0 < E_; k0 += 64) {
#pragma unroll
    for (int c = 0; c < 4; ++c) {
      int q = c * 256 + tid;
      int row = q >> 3, kc = (q & 7) * 8;
      int m = gm0 + row;
      int id = ids[(m & 15) * S_ + (m >> 4)];
      const float* ga = W_emb + (size_t)id * E_ + k0 + kc;
      floatx4 a0 = *(const floatx4*)ga;
      floatx4 a1 = *(const floatx4*)(ga + 4);
      *(shortx8*)&As[row * 72 + kc] = cvt8(a0, a1);
      const float* gb = W_ih + (size_t)(gn0 + row) * E_ + k0 + kc;
      floatx4 c0 = *(const floatx4*)gb;
      floatx4 c1 = *(const floatx4*)(gb + 4);
      *(shortx8*)&Bs[row * 72 + kc] = cvt8(c0, c1);
    }
    __syncthreads();
#pragma unroll
    for (int ks = 0; ks < 64; ks += 32) {
      shortx8 af[4], bfr[4];
#pragma unroll
      for (int i = 0; i < 4; ++i)
        af[i] = *(const shortx8*)&As[(wm + i * 16 + lr) * 72 + ks + lg * 8];
#pragma unroll
      for (int j = 0; j < 4; ++j)
        bfr[j] = *(const shortx8*)&Bs[(wn + j * 16 + lr) * 72 + ks + lg * 8];
#pragma unroll
      for (int i = 0; i < 4; ++i)
#pragma unroll
        for (int j = 0; j < 4; ++j) acc[i][j] = mfma_bf16(af[i], bfr[j], acc[i][j]);
    }
    __syncthreads();
  }
#pragma unroll
  for (int i = 0; i < 4; ++i) {
#pragma unroll
    for (int r = 0; r < 4; ++r) {
      int m = gm0 + wm + i * 16 + lg * 4 + r;
#pragma unroll
      for (int j = 0; j < 4; ++j) {
        int n = gn0 + wn + j * 16 + lr;
        pre[(size_t)m * H_ + n] = acc[i][j][r] + b_ih[n] + b_hh[n];
      }
    }
  }
}

// ---------------- persistent RNN kernel (32 blocks x 128) ----------------
// 2 waves/block, each wave owns 16 output columns with the FULL K=1024
// (W_hh fragments in 128 VGPRs/wave for all 128 steps; no LDS).
// h exchanged in fragment-linear global layout (elem (b,n) at
// ((n>>5)*64+((n>>3)&3)*16+b)*8+(n&7)) so A-frag loads are coalesced dwordx4.
// Sync protocol (the round-2 change):
//   arrival: all-threads workgroup release fence (drain own stores to L2)
//            -> __syncthreads -> thread0 agent RELEASE store to per-block flag
//            (ONE wbl2 per block per step).
//   wait:    RELAXED agent polls of the 32 per-block flags (sc1 read from IF$,
//            NO cache invalidate per iteration) by lanes tid<32,
//            then __syncthreads + ONE agent ACQUIRE fence (one buffer_inv).
//   pre[t+1] is prefetched into registers while polling.
__global__ __launch_bounds__(128, 1) void k_rnn(
    const float* __restrict__ hidden0, const float* __restrict__ W_hh,
    const float* __restrict__ pre, unsigned short* __restrict__ hb,  // [2][16*1024] bf16 frag-linear
    unsigned short* __restrict__ act,  // [b*128+t][1024] bf16
    float* __restrict__ hT_out,        // [16][1024] fp32 (d_out tail)
    int* __restrict__ flags) {         // 32 flags, stride 32 ints (128 B)
  const int tid = threadIdx.x, bid = blockIdx.x;
  const int lane = tid & 63, wave = tid >> 6;
  const int lr = lane & 15, lg = lane >> 4;
  const int nn = bid * 32 + wave * 16 + lr;  // this lane's output column

  // W_hh fragments -> registers, held across all steps.
  shortx8 bfr[32];
#pragma unroll
  for (int s = 0; s < 32; ++s) {
    const float* g = W_hh + (size_t)nn * H_ + s * 32 + lg * 8;
    floatx4 f0 = *(const floatx4*)g;
    floatx4 f1 = *(const floatx4*)(g + 4);
    bfr[s] = cvt8(f0, f1);
  }

  // h0 -> hb[0] fragment-linear bf16 (4 elems/thread over 32 blocks x 128)
  {
    int gt = (bid * 128 + tid) * 4;
#pragma unroll
    for (int u = 0; u < 4; ++u) {
      int e = gt + u;
      int b = e >> 10, n = e & 1023;
      hb[(((n >> 5) * 64 + ((n >> 3) & 3) * 16 + b) << 3) + (n & 7)] = f2b(hidden0[e]);
    }
  }

  __builtin_amdgcn_fence(__ATOMIC_RELEASE, "workgroup");  // drain own stores to L2
  __syncthreads();
  if (tid == 0)
    __hip_atomic_store(&flags[bid * 32], 1, __ATOMIC_RELEASE, __HIP_MEMORY_SCOPE_AGENT);

  // preload pre for t=0 (pre is ready: k_gemm_pre precedes us in-stream)
  float prer[4], prer2[4];
#pragma unroll
  for (int r = 0; r < 4; ++r) prer[r] = pre[((size_t)(lg * 4 + r)) * H_ + nn];

  if (tid < 32) {
    while (__hip_atomic_load(&flags[tid * 32], __ATOMIC_RELAXED,
                             __HIP_MEMORY_SCOPE_AGENT) < 1)
      __builtin_amdgcn_s_sleep(1);
  }
  __syncthreads();
  __builtin_amdgcn_fence(__ATOMIC_ACQUIRE, "agent");  // one inv; h0 now visible

  // fragment-linear store base for this lane's column nn (add b*8 per row)
  const int sft = (((nn >> 5) * 64 + ((nn >> 3) & 3) * 16) << 3) + (nn & 7);

  for (int t = 0; t < S_; ++t) {
    const unsigned short* hcur = hb + (t & 1) * (B_ * H_);
    unsigned short* hnxt = hb + ((t + 1) & 1) * (B_ * H_);

    // 32 MFMAs over full K, 4 interleaved accumulators
    floatx4 a0 = (floatx4)0.f, a1 = (floatx4)0.f, a2 = (floatx4)0.f, a3 = (floatx4)0.f;
#pragma unroll
    for (int s = 0; s < 32; s += 4) {
      shortx8 f0 = *(const shortx8*)&hcur[((s + 0) * 64 + lane) * 8];
      shortx8 f1 = *(const shortx8*)&hcur[((s + 1) * 64 + lane) * 8];
      shortx8 f2 = *(const shortx8*)&hcur[((s + 2) * 64 + lane) * 8];
      shortx8 f3 = *(const shortx8*)&hcur[((s + 3) * 64 + lane) * 8];
      a0 = mfma_bf16(f0, bfr[s + 0], a0);
      a1 = mfma_bf16(f1, bfr[s + 1], a1);
      a2 = mfma_bf16(f2, bfr[s + 2], a2);
      a3 = mfma_bf16(f3, bfr[s + 3], a3);
    }
    floatx4 acc = (a0 + a1) + (a2 + a3);

    // C/D: row b = lg*4 + r, col = nn
#pragma unroll
    for (int r = 0; r < 4; ++r) {
      int b = lg * 4 + r;
      float h = tanhf(acc[r] + prer[r]);
      unsigned short h16 = f2b(h);
      hnxt[sft + b * 8] = h16;
      act[((size_t)b * S_ + t) * H_ + nn] = h16;
      if (t == S_ - 1) hT_out[b * H_ + nn] = h;
    }

    if (t < S_ - 1) {
      __builtin_amdgcn_fence(__ATOMIC_RELEASE, "workgroup");  // drain own stores
      __syncthreads();
      if (tid == 0)
        __hip_atomic_store(&flags[bid * 32], t + 2, __ATOMIC_RELEASE,
                           __HIP_MEMORY_SCOPE_AGENT);
      // prefetch next-step pre into registers while we wait
#pragma unroll
      for (int r = 0; r < 4; ++r)
        prer2[r] = pre[((size_t)(t + 1) * B_ + lg * 4 + r) * H_ + nn];
      if (tid < 32) {
        while (__hip_atomic_load(&flags[tid * 32], __ATOMIC_RELAXED,
                                 __HIP_MEMORY_SCOPE_AGENT) < t + 2)
          __builtin_amdgcn_s_sleep(1);
      }
      __syncthreads();
      __builtin_amdgcn_fence(__ATOMIC_ACQUIRE, "agent");  // one inv per step
#pragma unroll
      for (int r = 0; r < 4; ++r) prer[r] = prer2[r];
    }
  }
}

// ---------------- decoder GEMM ----------------
// out[m][n] = act[m]·Wdec[n] + b_dec[n] + topic[n]*(stop[m]==0)
// M=2048, N=32000, K=1024. grid (250, 16), 256 threads.
__global__ __launch_bounds__(256, 2) void k_gemm_dec(
    const unsigned short* __restrict__ A, const unsigned short* __restrict__ Bw,
    const float* __restrict__ b_dec, const float* __restrict__ topic,
    const int* __restrict__ stop, float* __restrict__ out) {
  __shared__ unsigned short As[128 * 72];
  __shared__ unsigned short Bs[128 * 72];
  const int tid = threadIdx.x;
  const int gn0 = blockIdx.x * 128;
  const int gm0 = blockIdx.y * 128;
  const int wave = tid >> 6, lane = tid & 63;
  const int wm = (wave >> 1) * 64, wn = (wave & 1) * 64;
  const int lr = lane & 15, lg = lane >> 4;

  floatx4 acc[4][4];
#pragma unroll
  for (int i = 0; i < 4; ++i)
#pragma unroll
    for (int j = 0; j < 4; ++j) acc[i][j] = (floatx4)0.0f;

  for (int k0 = 0; k0 < H_; k0 += 64) {
#pragma unroll
    for (int c = 0; c < 4; ++c) {
      int q = c * 256 + tid;
      int row = q >> 3, kc = (q & 7) * 8;
      *(shortx8*)&As[row * 72 + kc] =
          *(const shortx8*)(A + (size_t)(gm0 + row) * H_ + k0 + kc);
      *(shortx8*)&Bs[row * 72 + kc] =
          *(const shortx8*)(Bw + (size_t)(gn0 + row) * H_ + k0 + kc);
    }
    __syncthreads();
#pragma unroll
    for (int ks = 0; ks < 64; ks += 32) {
      shortx8 af[4], bfr[4];
#pragma unroll
      for (int i = 0; i < 4; ++i)
        af[i] = *(const shortx8*)&As[(wm + i * 16 + lr) * 72 + ks + lg * 8];
#pragma unroll
      for (int j = 0; j < 4; ++j)
        bfr[j] = *(const shortx8*)&Bs[(wn + j * 16 + lr) * 72 + ks + lg * 8];
#pragma unroll
      for (int i = 0; i < 4; ++i)
#pragma unroll
        for (int j = 0; j < 4; ++j) acc[i][j] = mfma_bf16(af[i], bfr[j], acc[i][j]);
    }
    __syncthreads();
  }
#pragma unroll
  for (int i = 0; i < 4; ++i) {
#pragma unroll
    for (int r = 0; r < 4; ++r) {
      int m = gm0 + wm + i * 16 + lg * 4 + r;
      float msk = (stop[m] == 0) ? 1.f : 0.f;
      size_t base = (size_t)m * V_;
#pragma unroll
      for (int j = 0; j < 4; ++j) {
        int n = gn0 + wn + j * 16 + lr;
        out[base + n] = acc[i][j][r] + b_dec[n] + topic[n] * msk;
      }
    }
  }
}

// ---------------- launcher ----------------
extern "C" void kernel_launch(void* const* d_in, const int* in_sizes, int n_in,
                              void* d_out, int out_size, void* d_ws, size_t ws_size,
                              hipStream_t stream) {
  (void)in_sizes; (void)n_in; (void)out_size; (void)ws_size;
  const int*   ids    = (const int*)d_in[0];
  const float* hidden = (const float*)d_in[1];
  const int*   stop   = (const int*)d_in[2];
  const float* W_emb  = (const float*)d_in[3];
  const float* W_ih   = (const float*)d_in[4];
  const float* b_ih   = (const float*)d_in[5];
  const float* W_hh   = (const float*)d_in[6];
  const float* b_hh   = (const float*)d_in[7];
  const float* W_dec  = (const float*)d_in[8];
  const float* b_dec  = (const float*)d_in[9];
  const float* beta   = (const float*)d_in[10];
  const float* theta  = (const float*)d_in[11];
  float* out = (float*)d_out;

  char* ws = (char*)d_ws;
  size_t off = 0;
  auto alloc = [&](size_t bytes) -> void* {
    void* p = ws + off;
    off = (off + bytes + 255) & ~(size_t)255;
    return p;
  };
  int* flags = (int*)alloc(16384 * sizeof(int));  // 32 flags @128 B stride
  float* topic = (float*)alloc((size_t)V_ * 4);
  float* pre = (float*)alloc((size_t)B_ * S_ * H_ * 4);
  unsigned short* act = (unsigned short*)alloc((size_t)B_ * S_ * H_ * 2);
  unsigned short* hb = (unsigned short*)alloc((size_t)2 * B_ * H_ * 2);
  unsigned short* wdec16 = (unsigned short*)alloc((size_t)V_ * H_ * 2);

  k_zero<<<dim3(32), dim3(512), 0, stream>>>(flags, 16384);
  k_topic<<<dim3(V_ / 256), dim3(256), 0, stream>>>(beta, theta, topic);
  k_cvt<<<dim3((V_ * H_) / (256 * 8)), dim3(256), 0, stream>>>(W_dec, wdec16);
  k_gemm_pre<<<dim3(H_ / 128, (B_ * S_) / 128), dim3(256), 0, stream>>>(
      ids, W_emb, W_ih, b_ih, b_hh, pre);
  k_rnn<<<dim3(32), dim3(128), 0, stream>>>(hidden, W_hh, pre, hb, act,
                                            out + (size_t)B_ * S_ * V_, flags);
  k_gemm_dec<<<dim3(V_ / 128, (B_ * S_) / 128), dim3(256), 0, stream>>>(
      act, wdec16, b_dec, topic, stop, out);
}

// Round 3
// 1227.379 us; speedup vs baseline: 1.0473x; 1.0473x over previous
//
#include <hip/hip_runtime.h>
#include <stdint.h>

#define V_ 32000
#define E_ 512
#define H_ 1024
#define B_ 16
#define S_ 128
#define K_ 15

typedef float floatx4 __attribute__((ext_vector_type(4)));
typedef short shortx8 __attribute__((ext_vector_type(8)));
typedef __bf16 bf16x8 __attribute__((ext_vector_type(8)));

static __device__ __forceinline__ unsigned short f2b(float f) {
  union { float f; uint32_t u; } v; v.f = f;
  uint32_t u = v.u;
  u += 0x7FFFu + ((u >> 16) & 1u);   // round-to-nearest-even
  return (unsigned short)(u >> 16);
}

static __device__ __forceinline__ shortx8 cvt8(floatx4 a, floatx4 b) {
  shortx8 r;
  r[0] = (short)f2b(a[0]); r[1] = (short)f2b(a[1]);
  r[2] = (short)f2b(a[2]); r[3] = (short)f2b(a[3]);
  r[4] = (short)f2b(b[0]); r[5] = (short)f2b(b[1]);
  r[6] = (short)f2b(b[2]); r[7] = (short)f2b(b[3]);
  return r;
}

static __device__ __forceinline__ floatx4 mfma_bf16(shortx8 a, shortx8 b, floatx4 c) {
  return __builtin_amdgcn_mfma_f32_16x16x32_bf16(
      __builtin_bit_cast(bf16x8, a), __builtin_bit_cast(bf16x8, b), c, 0, 0, 0);
}

// write-through (IF$-resident) stores: leave NOTHING dirty in L2 -> no wbl2 on sync
static __device__ __forceinline__ void st_u16_wt(unsigned short* p, unsigned int v) {
  asm volatile("global_store_short %0, %1, off sc0 sc1" :: "v"(p), "v"(v) : "memory");
}
static __device__ __forceinline__ void st_u32_wt(int* p, int v) {
  asm volatile("global_store_dword %0, %1, off sc0 sc1" :: "v"(p), "v"(v) : "memory");
}
// cache-bypassing 8B load (sees IF$-fresh data; h addresses recur every 2 steps)
static __device__ __forceinline__ unsigned long long ld_u64_cb(const unsigned short* p) {
  return __hip_atomic_load((const unsigned long long*)p, __ATOMIC_RELAXED,
                           __HIP_MEMORY_SCOPE_AGENT);
}

// ---------------- tiny kernels ----------------

__global__ void k_zero(int* __restrict__ p, int n) {
  int i = blockIdx.x * blockDim.x + threadIdx.x;
  if (i < n) p[i] = 0;
}

// topic[n] = sum_k theta[k] * beta[k][n]   (grid 125x256 == 32000 exactly)
__global__ void k_topic(const float* __restrict__ beta, const float* __restrict__ theta,
                        float* __restrict__ topic) {
  int n = blockIdx.x * blockDim.x + threadIdx.x;
  float s = 0.f;
#pragma unroll
  for (int k = 0; k < K_; ++k) s += theta[k] * beta[k * V_ + n];
  topic[n] = s;
}

// fp32 -> bf16, 8 elems/thread. grid*block*8 must equal n exactly.
__global__ void k_cvt(const float* __restrict__ src, unsigned short* __restrict__ dst) {
  size_t i = (size_t)(blockIdx.x * blockDim.x + threadIdx.x) * 8;
  floatx4 f0 = *(const floatx4*)(src + i);
  floatx4 f1 = *(const floatx4*)(src + i + 4);
  *(shortx8*)(dst + i) = cvt8(f0, f1);
}

// ---------------- pre-projection GEMM ----------------
// pre[m=t*16+b][n] = sum_e W_emb[ids[b][t]][e]*W_ih[n][e] + b_ih[n] + b_hh[n]
// M=2048, N=1024, K=512. grid (N/128=8, M/128=16), 256 threads.
__global__ __launch_bounds__(256, 2) void k_gemm_pre(
    const int* __restrict__ ids, const float* __restrict__ W_emb,
    const float* __restrict__ W_ih, const float* __restrict__ b_ih,
    const float* __restrict__ b_hh, float* __restrict__ pre) {
  __shared__ unsigned short As[128 * 72];
  __shared__ unsigned short Bs[128 * 72];
  const int tid = threadIdx.x;
  const int gn0 = blockIdx.x * 128;
  const int gm0 = blockIdx.y * 128;
  const int wave = tid >> 6, lane = tid & 63;
  const int wm = (wave >> 1) * 64, wn = (wave & 1) * 64;
  const int lr = lane & 15, lg = lane >> 4;

  floatx4 acc[4][4];
#pragma unroll
  for (int i = 0; i < 4; ++i)
#pragma unroll
    for (int j = 0; j < 4; ++j) acc[i][j] = (floatx4)0.0f;

  for (int k0 = 0; k0 < E_; k0 += 64) {
#pragma unroll
    for (int c = 0; c < 4; ++c) {
      int q = c * 256 + tid;
      int row = q >> 3, kc = (q & 7) * 8;
      int m = gm0 + row;
      int id = ids[(m & 15) * S_ + (m >> 4)];
      const float* ga = W_emb + (size_t)id * E_ + k0 + kc;
      floatx4 a0 = *(const floatx4*)ga;
      floatx4 a1 = *(const floatx4*)(ga + 4);
      *(shortx8*)&As[row * 72 + kc] = cvt8(a0, a1);
      const float* gb = W_ih + (size_t)(gn0 + row) * E_ + k0 + kc;
      floatx4 c0 = *(const floatx4*)gb;
      floatx4 c1 = *(const floatx4*)(gb + 4);
      *(shortx8*)&Bs[row * 72 + kc] = cvt8(c0, c1);
    }
    __syncthreads();
#pragma unroll
    for (int ks = 0; ks < 64; ks += 32) {
      shortx8 af[4], bfr[4];
#pragma unroll
      for (int i = 0; i < 4; ++i)
        af[i] = *(const shortx8*)&As[(wm + i * 16 + lr) * 72 + ks + lg * 8];
#pragma unroll
      for (int j = 0; j < 4; ++j)
        bfr[j] = *(const shortx8*)&Bs[(wn + j * 16 + lr) * 72 + ks + lg * 8];
#pragma unroll
      for (int i = 0; i < 4; ++i)
#pragma unroll
        for (int j = 0; j < 4; ++j) acc[i][j] = mfma_bf16(af[i], bfr[j], acc[i][j]);
    }
    __syncthreads();
  }
#pragma unroll
  for (int i = 0; i < 4; ++i) {
#pragma unroll
    for (int r = 0; r < 4; ++r) {
      int m = gm0 + wm + i * 16 + lg * 4 + r;
#pragma unroll
      for (int j = 0; j < 4; ++j) {
        int n = gn0 + wn + j * 16 + lr;
        pre[(size_t)m * H_ + n] = acc[i][j][r] + b_ih[n] + b_hh[n];
      }
    }
  }
}

// ---------------- persistent RNN kernel (16 blocks x 256) ----------------
// Round-3 change: NO agent-release / NO fences anywhere in the step loop.
//   - h and flag stores are write-through (sc0 sc1) -> land at IF$, L2 never
//     dirty -> no buffer_wbl2 walk per step (the suspected ~3.5us/step cost).
//   - h loads / flag polls are relaxed agent atomics (sc1, cache-bypassing) --
//     required anyway since double-buffered h addresses recur every 2 steps.
//   - ordering: per-wave s_waitcnt vmcnt(0) before __syncthreads; thread0 then
//     publishes the flag; observers of the flag at IF$ see the h bytes at IF$.
//   - act/hT stores stay normal cached (consumer kernels run after dispatch-end
//     writeback). pre/W_hh reads stay cached; no buffer_inv left in the kernel.
__global__ __launch_bounds__(256, 1) void k_rnn(
    const float* __restrict__ hidden0, const float* __restrict__ W_hh,
    const float* __restrict__ pre, unsigned short* __restrict__ hb,  // [2][16*1024] bf16 frag-linear
    unsigned short* __restrict__ act,  // [b*128+t][1024] bf16
    float* __restrict__ hT_out,        // [16][1024] fp32 (d_out tail)
    int* __restrict__ flags) {         // 16 flags, stride 32 ints (128 B)
  const int tid = threadIdx.x, bid = blockIdx.x;
  const int lane = tid & 63, wave = tid >> 6;
  const int lr = lane & 15, lg = lane >> 4;
  const int nn = bid * 64 + wave * 16 + lr;  // this lane's output column

  // W_hh fragments -> registers, held across all steps (normal cached loads).
  shortx8 bfr[32];
#pragma unroll
  for (int s = 0; s < 32; ++s) {
    const float* g = W_hh + (size_t)nn * H_ + s * 32 + lg * 8;
    floatx4 f0 = *(const floatx4*)g;
    floatx4 f1 = *(const floatx4*)(g + 4);
    bfr[s] = cvt8(f0, f1);
  }

  // h0 -> hb[0] fragment-linear bf16, write-through (4 elems/thread, 16x256x4)
  {
    int gt = (bid * 256 + tid) * 4;
#pragma unroll
    for (int u = 0; u < 4; ++u) {
      int e = gt + u;
      int b = e >> 10, n = e & 1023;
      st_u16_wt(&hb[(((n >> 5) * 64 + ((n >> 3) & 3) * 16 + b) << 3) + (n & 7)],
                (unsigned int)f2b(hidden0[e]));
    }
  }
  asm volatile("s_waitcnt vmcnt(0)" ::: "memory");
  __syncthreads();
  if (tid == 0) st_u32_wt(&flags[bid * 32], 1);

  // preload pre for t=0 (normal cached load; pre GEMM precedes us in-stream)
  float prer[4], prer2[4];
#pragma unroll
  for (int r = 0; r < 4; ++r) prer[r] = pre[((size_t)(lg * 4 + r)) * H_ + nn];

  if (tid < 16) {
    while (__hip_atomic_load(&flags[tid * 32], __ATOMIC_RELAXED,
                             __HIP_MEMORY_SCOPE_AGENT) < 1)
      __builtin_amdgcn_s_sleep(1);
  }
  __syncthreads();

  // fragment-linear store base for this lane's column nn (add b*8 per row)
  const int sft = (((nn >> 5) * 64 + ((nn >> 3) & 3) * 16) << 3) + (nn & 7);

  for (int t = 0; t < S_; ++t) {
    const unsigned short* hcur = hb + (t & 1) * (B_ * H_);
    unsigned short* hnxt = hb + ((t + 1) & 1) * (B_ * H_);

    // 32 MFMAs over full K, 4 interleaved accumulators.
    // h loads are cache-bypassing 8B atomics (fresh from IF$).
    floatx4 a0 = (floatx4)0.f, a1 = (floatx4)0.f, a2 = (floatx4)0.f, a3 = (floatx4)0.f;
#pragma unroll
    for (int s = 0; s < 32; s += 4) {
      union { unsigned long long q[2]; shortx8 v; } u0, u1, u2, u3;
      const unsigned short* p0 = &hcur[((s + 0) * 64 + lane) * 8];
      const unsigned short* p1 = &hcur[((s + 1) * 64 + lane) * 8];
      const unsigned short* p2 = &hcur[((s + 2) * 64 + lane) * 8];
      const unsigned short* p3 = &hcur[((s + 3) * 64 + lane) * 8];
      u0.q[0] = ld_u64_cb(p0); u0.q[1] = ld_u64_cb(p0 + 4);
      u1.q[0] = ld_u64_cb(p1); u1.q[1] = ld_u64_cb(p1 + 4);
      u2.q[0] = ld_u64_cb(p2); u2.q[1] = ld_u64_cb(p2 + 4);
      u3.q[0] = ld_u64_cb(p3); u3.q[1] = ld_u64_cb(p3 + 4);
      a0 = mfma_bf16(u0.v, bfr[s + 0], a0);
      a1 = mfma_bf16(u1.v, bfr[s + 1], a1);
      a2 = mfma_bf16(u2.v, bfr[s + 2], a2);
      a3 = mfma_bf16(u3.v, bfr[s + 3], a3);
    }
    floatx4 acc = (a0 + a1) + (a2 + a3);

    // C/D: row b = lg*4 + r, col = nn
#pragma unroll
    for (int r = 0; r < 4; ++r) {
      int b = lg * 4 + r;
      float h = tanhf(acc[r] + prer[r]);
      unsigned short h16 = f2b(h);
      st_u16_wt(&hnxt[sft + b * 8], (unsigned int)h16);       // write-through
      act[((size_t)b * S_ + t) * H_ + nn] = h16;              // cached
      if (t == S_ - 1) hT_out[b * H_ + nn] = h;               // cached
    }

    if (t < S_ - 1) {
      asm volatile("s_waitcnt vmcnt(0)" ::: "memory");  // drain h stores (per wave)
      __syncthreads();
      if (tid == 0) st_u32_wt(&flags[bid * 32], t + 2);
      // prefetch next-step pre into registers while we wait (cached; never inv'd)
#pragma unroll
      for (int r = 0; r < 4; ++r)
        prer2[r] = pre[((size_t)(t + 1) * B_ + lg * 4 + r) * H_ + nn];
      if (tid < 16) {
        while (__hip_atomic_load(&flags[tid * 32], __ATOMIC_RELAXED,
                                 __HIP_MEMORY_SCOPE_AGENT) < t + 2)
          __builtin_amdgcn_s_sleep(1);
      }
      __syncthreads();
#pragma unroll
      for (int r = 0; r < 4; ++r) prer[r] = prer2[r];
    }
  }
}

// ---------------- decoder GEMM ----------------
// out[m][n] = act[m]·Wdec[n] + b_dec[n] + topic[n]*(stop[m]==0)
// M=2048, N=32000, K=1024. grid (250, 16), 256 threads.
__global__ __launch_bounds__(256, 2) void k_gemm_dec(
    const unsigned short* __restrict__ A, const unsigned short* __restrict__ Bw,
    const float* __restrict__ b_dec, const float* __restrict__ topic,
    const int* __restrict__ stop, float* __restrict__ out) {
  __shared__ unsigned short As[128 * 72];
  __shared__ unsigned short Bs[128 * 72];
  const int tid = threadIdx.x;
  const int gn0 = blockIdx.x * 128;
  const int gm0 = blockIdx.y * 128;
  const int wave = tid >> 6, lane = tid & 63;
  const int wm = (wave >> 1) * 64, wn = (wave & 1) * 64;
  const int lr = lane & 15, lg = lane >> 4;

  floatx4 acc[4][4];
#pragma unroll
  for (int i = 0; i < 4; ++i)
#pragma unroll
    for (int j = 0; j < 4; ++j) acc[i][j] = (floatx4)0.0f;

  for (int k0 = 0; k0 < H_; k0 += 64) {
#pragma unroll
    for (int c = 0; c < 4; ++c) {
      int q = c * 256 + tid;
      int row = q >> 3, kc = (q & 7) * 8;
      *(shortx8*)&As[row * 72 + kc] =
          *(const shortx8*)(A + (size_t)(gm0 + row) * H_ + k0 + kc);
      *(shortx8*)&Bs[row * 72 + kc] =
          *(const shortx8*)(Bw + (size_t)(gn0 + row) * H_ + k0 + kc);
    }
    __syncthreads();
#pragma unroll
    for (int ks = 0; ks < 64; ks += 32) {
      shortx8 af[4], bfr[4];
#pragma unroll
      for (int i = 0; i < 4; ++i)
        af[i] = *(const shortx8*)&As[(wm + i * 16 + lr) * 72 + ks + lg * 8];
#pragma unroll
      for (int j = 0; j < 4; ++j)
        bfr[j] = *(const shortx8*)&Bs[(wn + j * 16 + lr) * 72 + ks + lg * 8];
#pragma unroll
      for (int i = 0; i < 4; ++i)
#pragma unroll
        for (int j = 0; j < 4; ++j) acc[i][j] = mfma_bf16(af[i], bfr[j], acc[i][j]);
    }
    __syncthreads();
  }
#pragma unroll
  for (int i = 0; i < 4; ++i) {
#pragma unroll
    for (int r = 0; r < 4; ++r) {
      int m = gm0 + wm + i * 16 + lg * 4 + r;
      float msk = (stop[m] == 0) ? 1.f : 0.f;
      size_t base = (size_t)m * V_;
#pragma unroll
      for (int j = 0; j < 4; ++j) {
        int n = gn0 + wn + j * 16 + lr;
        out[base + n] = acc[i][j][r] + b_dec[n] + topic[n] * msk;
      }
    }
  }
}

// ---------------- launcher ----------------
extern "C" void kernel_launch(void* const* d_in, const int* in_sizes, int n_in,
                              void* d_out, int out_size, void* d_ws, size_t ws_size,
                              hipStream_t stream) {
  (void)in_sizes; (void)n_in; (void)out_size; (void)ws_size;
  const int*   ids    = (const int*)d_in[0];
  const float* hidden = (const float*)d_in[1];
  const int*   stop   = (const int*)d_in[2];
  const float* W_emb  = (const float*)d_in[3];
  const float* W_ih   = (const float*)d_in[4];
  const float* b_ih   = (const float*)d_in[5];
  const float* W_hh   = (const float*)d_in[6];
  const float* b_hh   = (const float*)d_in[7];
  const float* W_dec  = (const float*)d_in[8];
  const float* b_dec  = (const float*)d_in[9];
  const float* beta   = (const float*)d_in[10];
  const float* theta  = (const float*)d_in[11];
  float* out = (float*)d_out;

  char* ws = (char*)d_ws;
  size_t off = 0;
  auto alloc = [&](size_t bytes) -> void* {
    void* p = ws + off;
    off = (off + bytes + 255) & ~(size_t)255;
    return p;
  };
  int* flags = (int*)alloc(16384 * sizeof(int));  // 16 flags @128 B stride
  float* topic = (float*)alloc((size_t)V_ * 4);
  float* pre = (float*)alloc((size_t)B_ * S_ * H_ * 4);
  unsigned short* act = (unsigned short*)alloc((size_t)B_ * S_ * H_ * 2);
  unsigned short* hb = (unsigned short*)alloc((size_t)2 * B_ * H_ * 2);
  unsigned short* wdec16 = (unsigned short*)alloc((size_t)V_ * H_ * 2);

  k_zero<<<dim3(32), dim3(512), 0, stream>>>(flags, 16384);
  k_topic<<<dim3(V_ / 256), dim3(256), 0, stream>>>(beta, theta, topic);
  k_cvt<<<dim3((V_ * H_) / (256 * 8)), dim3(256), 0, stream>>>(W_dec, wdec16);
  k_gemm_pre<<<dim3(H_ / 128, (B_ * S_) / 128), dim3(256), 0, stream>>>(
      ids, W_emb, W_ih, b_ih, b_hh, pre);
  k_rnn<<<dim3(16), dim3(256), 0, stream>>>(hidden, W_hh, pre, hb, act,
                                            out + (size_t)B_ * S_ * V_, flags);
  k_gemm_dec<<<dim3(V_ / 128, (B_ * S_) / 128), dim3(256), 0, stream>>>(
      act, wdec16, b_dec, topic, stop, out);
}